// Round 6
// baseline (4206.119 us; speedup 1.0000x reference)
//
#include <hip/hip_runtime.h>

#define CC 56
#define TT 64
#define GRID 1024
#define NT 256
#define AGENT __HIP_MEMORY_SCOPE_AGENT

// bf16 region offsets (in ushort units) within each block's private weight cache
#define OAI 0
#define OAG 2048
#define OAO 4096
#define OCI 6144
#define OCG 8192
#define OCO 10240
#define OEI 12288
#define OEG 13312
#define OEO 14336
#define OBW 15360
#define OBV 16384
#define ODW 17408
#define ODV 18432
#define OFV 19456
#define RSTRIDE 20480            // ushorts per region (40960 B)

static __device__ __forceinline__ float wredsum(float v) {
#pragma unroll
  for (int m = 32; m; m >>= 1) v += __shfl_xor(v, m, 64);
  return v;
}
static __device__ __forceinline__ float sigm(float x) { return 1.f / (1.f + __expf(-x)); }
static __device__ __forceinline__ float ftanh(float x) {
  x = fminf(15.f, fmaxf(-15.f, x));
  float e = __expf(2.f * x);
  return (e - 1.f) / (e + 1.f);
}
static __device__ __forceinline__ float dot4(float4 a, float4 b) {
  return fmaf(a.x, b.x, fmaf(a.y, b.y, fmaf(a.z, b.z, a.w * b.w)));
}

// coherent (agent-scope write-through) accessors for cross-block data
static __device__ __forceinline__ float2 cld2(const float* p) {
  unsigned long long u = __hip_atomic_load((const unsigned long long*)p, __ATOMIC_RELAXED, AGENT);
  union { unsigned long long u; float2 f; } c; c.u = u; return c.f;
}
static __device__ __forceinline__ float4 cld4(const float* p) {
  float2 a = cld2(p), b = cld2(p + 2);
  return make_float4(a.x, a.y, b.x, b.y);
}
static __device__ __forceinline__ void cst1(float* p, float v) {
  __hip_atomic_store((unsigned int*)p, __float_as_uint(v), __ATOMIC_RELAXED, AGENT);
}
static __device__ __forceinline__ void cst2(float* p, float a, float b) {
  union { unsigned long long u; float2 f; } c; c.f = make_float2(a, b);
  __hip_atomic_store((unsigned long long*)p, c.u, __ATOMIC_RELAXED, AGENT);
}
static __device__ __forceinline__ void sti(int* p, int v) {
  __hip_atomic_store(p, v, __ATOMIC_RELAXED, AGENT);
}
static __device__ __forceinline__ unsigned long long ldl(const int* p) {
  return __hip_atomic_load((const unsigned long long*)p, __ATOMIC_RELAXED, AGENT);
}

// bf16 pack (RNE) and dot helpers
static __device__ __forceinline__ unsigned bfp(float lo, float hi) {
  unsigned a = __float_as_uint(lo), b = __float_as_uint(hi);
  a = (a + 0x7fffu + ((a >> 16) & 1u)) >> 16;
  b = (b + 0x7fffu + ((b >> 16) & 1u)) >> 16;
  return a | (b << 16);
}
static __device__ __forceinline__ float bdot2(uint2 w, float4 v) {
  float r = __uint_as_float(w.x << 16) * v.x;
  r = fmaf(__uint_as_float(w.x & 0xffff0000u), v.y, r);
  r = fmaf(__uint_as_float(w.y << 16), v.z, r);
  r = fmaf(__uint_as_float(w.y & 0xffff0000u), v.w, r);
  return r;
}
static __device__ __forceinline__ float bdot4(uint4 w, float4 a, float4 b) {
  return bdot2(make_uint2(w.x, w.y), a) + bdot2(make_uint2(w.z, w.w), b);
}

// converters: all NT threads cooperate on one row (n=2048 or 1024)
static __device__ __forceinline__ void cvt2048(unsigned short* dst, const float* src, int tid) {
  const float4* s4 = (const float4*)src;
  float4 x = s4[tid * 2], y = s4[tid * 2 + 1];
  ((uint4*)dst)[tid] = make_uint4(bfp(x.x, x.y), bfp(x.z, x.w), bfp(y.x, y.y), bfp(y.z, y.w));
}
static __device__ __forceinline__ void cvt1024(unsigned short* dst, const float* src, int tid) {
  float4 x = ((const float4*)src)[tid];
  ((uint2*)dst)[tid] = make_uint2(bfp(x.x, x.y), bfp(x.z, x.w));
}

// ---- flat direct-poll barrier: packed 4B slots, every block polls all 1024 itself.
// No init needed: 0xAA poison is negative as int, g is monotone positive.
static __device__ __forceinline__ void warr(int* slots, int g, int b) {
  __syncthreads();                 // drains each wave's write-through stores (vmcnt 0)
  if (threadIdx.x == 0) sti(slots + b, g);
}
static __device__ __forceinline__ void wwait(int* slots, int g, int* okp) {
  const int tid = threadIdx.x;
  const int* p = slots + 4 * tid;  // 4 consecutive slots per thread
  for (;;) {
    if (tid == 0) *okp = 1;
    __syncthreads();
    unsigned long long u0 = ldl(p), u1 = ldl(p + 2);
    if ((int)u0 < g || (int)(u0 >> 32) < g || (int)u1 < g || (int)(u1 >> 32) < g) *okp = 0;
    __syncthreads();
    if (*okp) break;
    __builtin_amdgcn_s_sleep(4);
  }
  __asm__ __volatile__("" ::: "memory");
}

__global__ void __launch_bounds__(NT, 4) predcells(
    const float* __restrict__ inp,
    const float* __restrict__ W0w, const float* __restrict__ W0b,
    const float* __restrict__ W1w, const float* __restrict__ W1b,
    const float* __restrict__ W2w, const float* __restrict__ W2b,
    const float* __restrict__ Wi1, const float* __restrict__ b1,
    const float* __restrict__ Wi2, const float* __restrict__ b2,
    const float* __restrict__ Wi3, const float* __restrict__ b3,
    const float* __restrict__ V1w, const float* __restrict__ V1b,
    const float* __restrict__ V2w, const float* __restrict__ V2b,
    const float* __restrict__ V3w, const float* __restrict__ V3b,
    const int* __restrict__ itn,
    float* __restrict__ out, int* iws, float* fws, unsigned short* wbf)
{
  const int tid = threadIdx.x;
  const int lane = tid & 63;
  const int wv = tid >> 6;
  const int b = blockIdx.x;
  const int wb = b;
  const int vb = wb - 512;
  const bool hasV1 = (vb >= 0 && vb < CC);

  float* TD1 = fws;            // 1024
  float* TD2 = fws + 1024;     // 1024
  float* recon1 = fws + 2048;  // 64 (56 used)
  float* recon2 = fws + 2112;  // 1024
  float* recon3 = fws + 3136;  // 1024
  float* BU0 = fws + 4160;     // 1024
  float* s1  = fws + 5184;     // 1024
  float* BU1 = fws + 6208;     // 1024
  float* s2  = fws + 7232;     // 1024
  float* BU2 = fws + 8256;     // 1024
  float* s3  = fws + 9280;     // 1024

  __shared__ float ps[4][4];
  __shared__ int ok;

  unsigned short* reg = wbf + (size_t)b * RSTRIDE;   // this block's private bf16 weight cache

  // ---- preloop 1: convert this block's own weight rows to bf16 (block-private, no sync needed)
  cvt2048(reg + OAI, Wi1 + (size_t)wb * 2048, tid);
  cvt2048(reg + OAG, Wi1 + (size_t)(wb + 2048) * 2048, tid);
  cvt2048(reg + OAO, Wi1 + (size_t)(wb + 3072) * 2048, tid);
  cvt2048(reg + OCI, Wi2 + (size_t)wb * 2048, tid);
  cvt2048(reg + OCG, Wi2 + (size_t)(wb + 2048) * 2048, tid);
  cvt2048(reg + OCO, Wi2 + (size_t)(wb + 3072) * 2048, tid);
  cvt1024(reg + OEI, Wi3 + (size_t)wb * 1024, tid);
  cvt1024(reg + OEG, Wi3 + (size_t)(wb + 2048) * 1024, tid);
  cvt1024(reg + OEO, Wi3 + (size_t)(wb + 3072) * 1024, tid);
  cvt1024(reg + OBW, W1w + (size_t)wb * 1024, tid);
  if (hasV1) cvt1024(reg + OBV, V1w + (size_t)vb * 1024, tid);
  cvt1024(reg + ODW, W2w + (size_t)wb * 1024, tid);
  cvt1024(reg + ODV, V2w + (size_t)wb * 1024, tid);
  cvt1024(reg + OFV, V3w + (size_t)wb * 1024, tid);

  // ---- hoisted block-constant scalars
  const float lam = (itn[0] <= 1000) ? 1e-4f : 1e-2f;
  const float lam2 = lam * lam;
  const float b1i = b1[wb], b1g = b1[wb + 2048], b1o = b1[wb + 3072];
  const float b2i = b2[wb], b2g = b2[wb + 2048], b2o = b2[wb + 3072];
  const float b3i = b3[wb], b3g = b3[wb + 2048], b3o = b3[wb + 3072];
  const float w1br = W1b[wb], w2br = W2b[wb], v2br = V2b[wb], v3br = V3b[wb], w0br = W0b[wb];
  const float v1br = hasV1 ? V1b[vb] : 0.f;
  float loss = 0.f;  // block0 tid0 only

  // ---- preloop 2: block0 zeroes carries; every block computes BU0(t=0)
  if (b == 0) {
    for (int i = tid * 2; i < 4160; i += NT * 2) cst2(fws + i, 0.f, 0.f);
  }
  if (wv == 0) {  // nTD0(t=0) = x_0 (recon1 zero)
    float acc = 0.f, ls = 0.f;
    if (lane < 14) {
      const float4 a  = ((const float4*)(W0w + wb * CC))[lane];
      const float4 xv = ((const float4*)inp)[lane];
      acc = dot4(a, xv);
      ls = fabsf(xv.x) + fabsf(xv.y) + fabsf(xv.z) + fabsf(xv.w);
    }
    acc = wredsum(acc);
    ls  = wredsum(ls);
    if (lane == 0) cst1(&BU0[wb], acc + w0br);
    if (b == 0 && lane == 0) loss += ls;
  }
  int g = 1;
  warr(iws, g, b);

  for (int t = 0; t < TT; ++t) {
    // ======== prefetch A: own bf16 rows (always safe) + TD1 for waves 2,3 (written B_{t-1})
    uint4 wAi = ((const uint4*)(reg + OAI))[tid];
    uint4 wAg = ((const uint4*)(reg + OAG))[tid];
    uint4 wAo = ((const uint4*)(reg + OAO))[tid];
    float4 tA0, tA1;
    if (wv >= 2) { tA0 = cld4(TD1 + tid * 8 - 1024); tA1 = cld4(TD1 + tid * 8 - 1020); }
    wwait(iws, g, &ok);
    // ---- A: s1 = lstm(Wi1 @ [BU0;TD1] + b1)
    {
      float4 v0, v1;
      if (wv < 2) { v0 = cld4(BU0 + tid * 8); v1 = cld4(BU0 + tid * 8 + 4); }
      else if (t == 0) { v0 = make_float4(0.f, 0.f, 0.f, 0.f); v1 = v0; }
      else { v0 = tA0; v1 = tA1; }
      float zi = wredsum(bdot4(wAi, v0, v1));
      float zg = wredsum(bdot4(wAg, v0, v1));
      float zo = wredsum(bdot4(wAo, v0, v1));
      if (lane == 0) { ps[0][wv] = zi; ps[1][wv] = zg; ps[2][wv] = zo; }
      __syncthreads();
      if (tid == 0) {
        float ZI = ps[0][0] + ps[0][1] + ps[0][2] + ps[0][3] + b1i;
        float ZG = ps[1][0] + ps[1][1] + ps[1][2] + ps[1][3] + b1g;
        float ZO = ps[2][0] + ps[2][1] + ps[2][2] + ps[2][3] + b1o;
        cst1(&s1[wb], sigm(ZO) * ftanh(sigm(ZI) * ftanh(ZG)));
      }
    }
    warr(iws, ++g, b);

    // ======== prefetch B: W1/V1 bf16 rows + recon2 (written D_{t-1}/preloop)
    uint2 wB1 = ((const uint2*)(reg + OBW))[tid];
    uint2 wBV; if (hasV1) wBV = ((const uint2*)(reg + OBV))[tid];
    float4 rv2 = cld4(recon2 + tid * 4);
    wwait(iws, g, &ok);
    // ---- B: nTD1 = s1-recon2; BU1 = W1@nTD1+b; recon1 = V1@s1+b; TD1<-nTD1; loss += lam*|nTD1|
    {
      float4 sv = cld4(s1 + tid * 4);
      float4 d = make_float4(sv.x - rv2.x, sv.y - rv2.y, sv.z - rv2.z, sv.w - rv2.w);
      float pw = wredsum(bdot2(wB1, d));
      if (lane == 0) ps[0][wv] = pw;
      if (hasV1) {
        float pv = wredsum(bdot2(wBV, sv));
        if (lane == 0) ps[1][wv] = pv;
      }
      if (b == 0) {
        cst2(TD1 + tid * 4, d.x, d.y);
        cst2(TD1 + tid * 4 + 2, d.z, d.w);
        float l = wredsum(fabsf(d.x) + fabsf(d.y) + fabsf(d.z) + fabsf(d.w));
        if (lane == 0) ps[2][wv] = l;
      }
      __syncthreads();
      if (tid == 0) {
        cst1(&BU1[wb], ps[0][0] + ps[0][1] + ps[0][2] + ps[0][3] + w1br);
        if (hasV1) cst1(&recon1[vb], ps[1][0] + ps[1][1] + ps[1][2] + ps[1][3] + v1br);
        if (b == 0) loss += lam * (ps[2][0] + ps[2][1] + ps[2][2] + ps[2][3]);
      }
    }
    warr(iws, ++g, b);

    // ======== prefetch C: Wi2 bf16 rows + TD2 for waves 2,3 (written D_{t-1}/preloop)
    uint4 wCi = ((const uint4*)(reg + OCI))[tid];
    uint4 wCg = ((const uint4*)(reg + OCG))[tid];
    uint4 wCo = ((const uint4*)(reg + OCO))[tid];
    float4 tC0, tC1;
    if (wv >= 2) { tC0 = cld4(TD2 + tid * 8 - 1024); tC1 = cld4(TD2 + tid * 8 - 1020); }
    wwait(iws, g, &ok);
    // ---- C: s2 = lstm(Wi2 @ [BU1;TD2] + b2)
    {
      float4 v0, v1;
      if (wv < 2) { v0 = cld4(BU1 + tid * 8); v1 = cld4(BU1 + tid * 8 + 4); }
      else { v0 = tC0; v1 = tC1; }
      float zi = wredsum(bdot4(wCi, v0, v1));
      float zg = wredsum(bdot4(wCg, v0, v1));
      float zo = wredsum(bdot4(wCo, v0, v1));
      if (lane == 0) { ps[0][wv] = zi; ps[1][wv] = zg; ps[2][wv] = zo; }
      __syncthreads();
      if (tid == 0) {
        float ZI = ps[0][0] + ps[0][1] + ps[0][2] + ps[0][3] + b2i;
        float ZG = ps[1][0] + ps[1][1] + ps[1][2] + ps[1][3] + b2g;
        float ZO = ps[2][0] + ps[2][1] + ps[2][2] + ps[2][3] + b2o;
        cst1(&s2[wb], sigm(ZO) * ftanh(sigm(ZI) * ftanh(ZG)));
      }
    }
    warr(iws, ++g, b);

    // ======== prefetch D: W2/V2 bf16 rows + recon3 (written F_{t-1}/preloop)
    uint2 wD2 = ((const uint2*)(reg + ODW))[tid];
    uint2 wDV = ((const uint2*)(reg + ODV))[tid];
    float4 rv3 = cld4(recon3 + tid * 4);
    wwait(iws, g, &ok);
    // ---- D: nTD2 = s2-recon3; BU2 = W2@nTD2+b; recon2 = V2@s2+b; TD2<-nTD2; loss += lam2*|nTD2|
    {
      float4 sv = cld4(s2 + tid * 4);
      float4 d = make_float4(sv.x - rv3.x, sv.y - rv3.y, sv.z - rv3.z, sv.w - rv3.w);
      float pw = wredsum(bdot2(wD2, d));
      float pv = wredsum(bdot2(wDV, sv));
      if (lane == 0) { ps[0][wv] = pw; ps[1][wv] = pv; }
      if (b == 0) {
        cst2(TD2 + tid * 4, d.x, d.y);
        cst2(TD2 + tid * 4 + 2, d.z, d.w);
        float l = wredsum(fabsf(d.x) + fabsf(d.y) + fabsf(d.z) + fabsf(d.w));
        if (lane == 0) ps[2][wv] = l;
      }
      __syncthreads();
      if (tid == 0) {
        cst1(&BU2[wb],    ps[0][0] + ps[0][1] + ps[0][2] + ps[0][3] + w2br);
        cst1(&recon2[wb], ps[1][0] + ps[1][1] + ps[1][2] + ps[1][3] + v2br);
        if (b == 0) loss += lam2 * (ps[2][0] + ps[2][1] + ps[2][2] + ps[2][3]);
      }
    }
    warr(iws, ++g, b);

    // ======== prefetch E: Wi3 bf16 rows
    uint2 wEi = ((const uint2*)(reg + OEI))[tid];
    uint2 wEg = ((const uint2*)(reg + OEG))[tid];
    uint2 wEo = ((const uint2*)(reg + OEO))[tid];
    wwait(iws, g, &ok);
    // ---- E: s3 = lstm(Wi3 @ BU2 + b3)
    {
      float4 v0 = cld4(BU2 + tid * 4);
      float zi = wredsum(bdot2(wEi, v0));
      float zg = wredsum(bdot2(wEg, v0));
      float zo = wredsum(bdot2(wEo, v0));
      if (lane == 0) { ps[0][wv] = zi; ps[1][wv] = zg; ps[2][wv] = zo; }
      __syncthreads();
      if (tid == 0) {
        float ZI = ps[0][0] + ps[0][1] + ps[0][2] + ps[0][3] + b3i;
        float ZG = ps[1][0] + ps[1][1] + ps[1][2] + ps[1][3] + b3g;
        float ZO = ps[2][0] + ps[2][1] + ps[2][2] + ps[2][3] + b3o;
        cst1(&s3[wb], sigm(ZO) * ftanh(sigm(ZI) * ftanh(ZG)));
      }
    }
    warr(iws, ++g, b);

    // ======== prefetch F: V3 bf16 row; wave1: W0 row (fp32), x_{t+1}, recon1 (written B_t)
    uint2 wFV = ((const uint2*)(reg + OFV))[tid];
    float4 w0r, xnx, rc1;
    if (wv == 1 && lane < 14) {
      const int tn = (t < TT - 1) ? (t + 1) : (TT - 1);
      w0r = ((const float4*)(W0w + wb * CC))[lane];
      xnx = ((const float4*)(inp + tn * CC))[lane];
      rc1 = cld4(recon1 + lane * 4);
    }
    wwait(iws, g, &ok);
    // ---- F: recon3 = V3@s3+b ; BU0(t+1) = W0@(x_{t+1}-recon1)+W0b ; loss += |nTD0|
    {
      float4 v0 = cld4(s3 + tid * 4);
      float pv = wredsum(bdot2(wFV, v0));
      if (lane == 0) ps[0][wv] = pv;
      if (t < TT - 1 && wv == 1) {
        float acc = 0.f, ls = 0.f;
        if (lane < 14) {
          float4 dd = make_float4(xnx.x - rc1.x, xnx.y - rc1.y, xnx.z - rc1.z, xnx.w - rc1.w);
          acc = dot4(w0r, dd);
          ls = fabsf(dd.x) + fabsf(dd.y) + fabsf(dd.z) + fabsf(dd.w);
        }
        acc = wredsum(acc);
        ls  = wredsum(ls);
        if (lane == 0) { cst1(&BU0[wb], acc + w0br); ps[1][0] = ls; }
      }
      __syncthreads();
      if (tid == 0) {
        cst1(&recon3[wb], ps[0][0] + ps[0][1] + ps[0][2] + ps[0][3] + v3br);
        if (b == 0 && t < TT - 1) loss += ps[1][0];
      }
    }
    warr(iws, ++g, b);
  }

  if (b == 0 && tid == 0) out[0] = loss;
}

extern "C" void kernel_launch(void* const* d_in, const int* in_sizes, int n_in,
                              void* d_out, int out_size, void* d_ws, size_t ws_size,
                              hipStream_t stream) {
  const float* inp = (const float*)d_in[0];
  const float* W0w = (const float*)d_in[1];
  const float* W0b = (const float*)d_in[2];
  const float* W1w = (const float*)d_in[3];
  const float* W1b = (const float*)d_in[4];
  const float* W2w = (const float*)d_in[5];
  const float* W2b = (const float*)d_in[6];
  const float* Wi1 = (const float*)d_in[7];
  const float* b1  = (const float*)d_in[8];
  const float* Wi2 = (const float*)d_in[9];
  const float* b2  = (const float*)d_in[10];
  const float* Wi3 = (const float*)d_in[11];
  const float* b3  = (const float*)d_in[12];
  const float* V1w = (const float*)d_in[13];
  const float* V1b = (const float*)d_in[14];
  const float* V2w = (const float*)d_in[15];
  const float* V2b = (const float*)d_in[16];
  const float* V3w = (const float*)d_in[17];
  const float* V3b = (const float*)d_in[18];
  const int*   itn = (const int*)d_in[19];

  int*            iws = (int*)d_ws;                                  // 4 KB packed barrier slots
  float*          fws = (float*)((char*)d_ws + 65536);               // carry/stage vectors (~41 KB)
  unsigned short* wbf = (unsigned short*)((char*)d_ws + 131072);     // 1024 × 40 KB bf16 weight regions

  hipLaunchKernelGGL(predcells, dim3(GRID), dim3(NT), 0, stream,
                     inp, W0w, W0b, W1w, W1b, W2w, W2b,
                     Wi1, b1, Wi2, b2, Wi3, b3,
                     V1w, V1b, V2w, V2b, V3w, V3b, itn,
                     (float*)d_out, iws, fws, wbf);
}

// Round 7
// 1704.945 us; speedup vs baseline: 2.4670x; 2.4670x over previous
//
#include <hip/hip_runtime.h>

#define CC 56
#define TT 64
#define GRID 1024
#define NT 256
#define NFLAG 64
#define SS 32                    // 128 B stride between sync slots
#define FB (GRID * SS)           // flag base (int index)
#define AGENT __HIP_MEMORY_SCOPE_AGENT

// bf16 region offsets (in ushort units) within each block's private weight cache
#define OAI 0
#define OAG 2048
#define OAO 4096
#define OCI 6144
#define OCG 8192
#define OCO 10240
#define OEI 12288
#define OEG 13312
#define OEO 14336
#define OBW 15360
#define OBV 16384
#define ODW 17408
#define ODV 18432
#define OFV 19456
#define RSTRIDE 20480            // ushorts per region (40960 B)

static __device__ __forceinline__ float wredsum(float v) {
#pragma unroll
  for (int m = 32; m; m >>= 1) v += __shfl_xor(v, m, 64);
  return v;
}
static __device__ __forceinline__ float sigm(float x) { return 1.f / (1.f + __expf(-x)); }
static __device__ __forceinline__ float ftanh(float x) {
  x = fminf(15.f, fmaxf(-15.f, x));
  float e = __expf(2.f * x);
  return (e - 1.f) / (e + 1.f);
}
static __device__ __forceinline__ float dot4(float4 a, float4 b) {
  return fmaf(a.x, b.x, fmaf(a.y, b.y, fmaf(a.z, b.z, a.w * b.w)));
}

// coherent (agent-scope write-through) accessors for cross-block data
static __device__ __forceinline__ float2 cld2(const float* p) {
  unsigned long long u = __hip_atomic_load((const unsigned long long*)p, __ATOMIC_RELAXED, AGENT);
  union { unsigned long long u; float2 f; } c; c.u = u; return c.f;
}
static __device__ __forceinline__ float4 cld4(const float* p) {
  float2 a = cld2(p), b = cld2(p + 2);
  return make_float4(a.x, a.y, b.x, b.y);
}
static __device__ __forceinline__ void cst1(float* p, float v) {
  __hip_atomic_store((unsigned int*)p, __float_as_uint(v), __ATOMIC_RELAXED, AGENT);
}
static __device__ __forceinline__ void cst2(float* p, float a, float b) {
  union { unsigned long long u; float2 f; } c; c.f = make_float2(a, b);
  __hip_atomic_store((unsigned long long*)p, c.u, __ATOMIC_RELAXED, AGENT);
}
static __device__ __forceinline__ int ldi(const int* p) {
  return __hip_atomic_load(p, __ATOMIC_RELAXED, AGENT);
}
static __device__ __forceinline__ void sti(int* p, int v) {
  __hip_atomic_store(p, v, __ATOMIC_RELAXED, AGENT);
}

// bf16 pack (RNE) and dot helpers
static __device__ __forceinline__ unsigned bfp(float lo, float hi) {
  unsigned a = __float_as_uint(lo), b = __float_as_uint(hi);
  a = (a + 0x7fffu + ((a >> 16) & 1u)) >> 16;
  b = (b + 0x7fffu + ((b >> 16) & 1u)) >> 16;
  return a | (b << 16);
}
static __device__ __forceinline__ float bdot2(uint2 w, float4 v) {
  float r = __uint_as_float(w.x << 16) * v.x;
  r = fmaf(__uint_as_float(w.x & 0xffff0000u), v.y, r);
  r = fmaf(__uint_as_float(w.y << 16), v.z, r);
  r = fmaf(__uint_as_float(w.y & 0xffff0000u), v.w, r);
  return r;
}
static __device__ __forceinline__ float bdot4(uint4 w, float4 a, float4 b) {
  return bdot2(make_uint2(w.x, w.y), a) + bdot2(make_uint2(w.z, w.w), b);
}

// converters: all NT threads cooperate on one row (n=2048 or 1024)
static __device__ __forceinline__ void cvt2048(unsigned short* dst, const float* src, int tid) {
  const float4* s4 = (const float4*)src;
  float4 x = s4[tid * 2], y = s4[tid * 2 + 1];
  ((uint4*)dst)[tid] = make_uint4(bfp(x.x, x.y), bfp(x.z, x.w), bfp(y.x, y.y), bfp(y.z, y.w));
}
static __device__ __forceinline__ void cvt1024(unsigned short* dst, const float* src, int tid) {
  float4 x = ((const float4*)src)[tid];
  ((uint2*)dst)[tid] = make_uint2(bfp(x.x, x.y), bfp(x.z, x.w));
}

// ---- round-5 master-relay barrier (all-relaxed, measured ~2.5 µs). No init needed:
// 0xAA poison is negative as int, g is monotone positive.
static __device__ __forceinline__ void warr(int* iws, int g, int b) {
  __syncthreads();                 // drains each wave's write-through stores (vmcnt 0)
  if (threadIdx.x == 0) sti(iws + SS * b, g);
}
static __device__ __forceinline__ void wwait(int* iws, int g, int b) {
  if (b == 0) {  // master: batched poll, 4 independent strided loads per sweep; no flag spin
    const int* p0 = iws + SS * threadIdx.x;
    for (;;) {
      int a0 = ldi(p0), a1 = ldi(p0 + SS * 256), a2 = ldi(p0 + SS * 512), a3 = ldi(p0 + SS * 768);
      if (a0 >= g && a1 >= g && a2 >= g && a3 >= g) break;
      __builtin_amdgcn_s_sleep(1);
    }
    __syncthreads();
    if (threadIdx.x < NFLAG) sti(iws + FB + SS * threadIdx.x, g);
  } else {
    if (threadIdx.x == 0)
      while (ldi(iws + FB + SS * (b & (NFLAG - 1))) < g) __builtin_amdgcn_s_sleep(1);
  }
  __asm__ __volatile__("" ::: "memory");  // no load hoisting above the spin
  __syncthreads();
}

__global__ void __launch_bounds__(NT, 4) predcells(
    const float* __restrict__ inp,
    const float* __restrict__ W0w, const float* __restrict__ W0b,
    const float* __restrict__ W1w, const float* __restrict__ W1b,
    const float* __restrict__ W2w, const float* __restrict__ W2b,
    const float* __restrict__ Wi1, const float* __restrict__ b1,
    const float* __restrict__ Wi2, const float* __restrict__ b2,
    const float* __restrict__ Wi3, const float* __restrict__ b3,
    const float* __restrict__ V1w, const float* __restrict__ V1b,
    const float* __restrict__ V2w, const float* __restrict__ V2b,
    const float* __restrict__ V3w, const float* __restrict__ V3b,
    const int* __restrict__ itn,
    float* __restrict__ out, int* iws, float* fws, unsigned short* wbf)
{
  const int tid = threadIdx.x;
  const int lane = tid & 63;
  const int wv = tid >> 6;
  const int b = blockIdx.x;
  const int wb = b;
  const int vb = wb - 512;
  const bool hasV1 = (vb >= 0 && vb < CC);

  float* TD1 = fws;            // 1024
  float* TD2 = fws + 1024;     // 1024
  float* recon1 = fws + 2048;  // 64 (56 used)
  float* recon2 = fws + 2112;  // 1024
  float* recon3 = fws + 3136;  // 1024
  float* BU0 = fws + 4160;     // 1024
  float* s1  = fws + 5184;     // 1024
  float* BU1 = fws + 6208;     // 1024
  float* s2  = fws + 7232;     // 1024
  float* BU2 = fws + 8256;     // 1024
  float* s3  = fws + 9280;     // 1024

  __shared__ float ps[4][4];

  unsigned short* reg = wbf + (size_t)b * RSTRIDE;   // this block's private bf16 weight cache

  // ---- preloop 1: convert this block's own weight rows to bf16 (block-private, no sync needed)
  cvt2048(reg + OAI, Wi1 + (size_t)wb * 2048, tid);
  cvt2048(reg + OAG, Wi1 + (size_t)(wb + 2048) * 2048, tid);
  cvt2048(reg + OAO, Wi1 + (size_t)(wb + 3072) * 2048, tid);
  cvt2048(reg + OCI, Wi2 + (size_t)wb * 2048, tid);
  cvt2048(reg + OCG, Wi2 + (size_t)(wb + 2048) * 2048, tid);
  cvt2048(reg + OCO, Wi2 + (size_t)(wb + 3072) * 2048, tid);
  cvt1024(reg + OEI, Wi3 + (size_t)wb * 1024, tid);
  cvt1024(reg + OEG, Wi3 + (size_t)(wb + 2048) * 1024, tid);
  cvt1024(reg + OEO, Wi3 + (size_t)(wb + 3072) * 1024, tid);
  cvt1024(reg + OBW, W1w + (size_t)wb * 1024, tid);
  if (hasV1) cvt1024(reg + OBV, V1w + (size_t)vb * 1024, tid);
  cvt1024(reg + ODW, W2w + (size_t)wb * 1024, tid);
  cvt1024(reg + ODV, V2w + (size_t)wb * 1024, tid);
  cvt1024(reg + OFV, V3w + (size_t)wb * 1024, tid);

  // ---- hoisted block-constant scalars
  const float lam = (itn[0] <= 1000) ? 1e-4f : 1e-2f;
  const float lam2 = lam * lam;
  const float b1i = b1[wb], b1g = b1[wb + 2048], b1o = b1[wb + 3072];
  const float b2i = b2[wb], b2g = b2[wb + 2048], b2o = b2[wb + 3072];
  const float b3i = b3[wb], b3g = b3[wb + 2048], b3o = b3[wb + 3072];
  const float w1br = W1b[wb], w2br = W2b[wb], v2br = V2b[wb], v3br = V3b[wb], w0br = W0b[wb];
  const float v1br = hasV1 ? V1b[vb] : 0.f;
  float loss = 0.f;  // block0 tid0 only

  // ---- preloop 2: block0 zeroes carries; every block computes BU0(t=0)
  if (b == 0) {
    for (int i = tid * 2; i < 4160; i += NT * 2) cst2(fws + i, 0.f, 0.f);
  }
  if (wv == 0) {  // nTD0(t=0) = x_0 (recon1 zero)
    float acc = 0.f, ls = 0.f;
    if (lane < 14) {
      const float4 a  = ((const float4*)(W0w + wb * CC))[lane];
      const float4 xv = ((const float4*)inp)[lane];
      acc = dot4(a, xv);
      ls = fabsf(xv.x) + fabsf(xv.y) + fabsf(xv.z) + fabsf(xv.w);
    }
    acc = wredsum(acc);
    ls  = wredsum(ls);
    if (lane == 0) cst1(&BU0[wb], acc + w0br);
    if (b == 0 && lane == 0) loss += ls;
  }
  int g = 1;
  warr(iws, g, b);

  for (int t = 0; t < TT; ++t) {
    // ======== prefetch A: own bf16 rows (always safe) + TD1 for waves 2,3 (written B_{t-1})
    uint4 wAi = ((const uint4*)(reg + OAI))[tid];
    uint4 wAg = ((const uint4*)(reg + OAG))[tid];
    uint4 wAo = ((const uint4*)(reg + OAO))[tid];
    float4 tA0, tA1;
    if (wv >= 2) { tA0 = cld4(TD1 + tid * 8 - 1024); tA1 = cld4(TD1 + tid * 8 - 1020); }
    wwait(iws, g, b);
    // ---- A: s1 = lstm(Wi1 @ [BU0;TD1] + b1)
    {
      float4 v0, v1;
      if (wv < 2) { v0 = cld4(BU0 + tid * 8); v1 = cld4(BU0 + tid * 8 + 4); }
      else if (t == 0) { v0 = make_float4(0.f, 0.f, 0.f, 0.f); v1 = v0; }
      else { v0 = tA0; v1 = tA1; }
      float zi = wredsum(bdot4(wAi, v0, v1));
      float zg = wredsum(bdot4(wAg, v0, v1));
      float zo = wredsum(bdot4(wAo, v0, v1));
      if (lane == 0) { ps[0][wv] = zi; ps[1][wv] = zg; ps[2][wv] = zo; }
      __syncthreads();
      if (tid == 0) {
        float ZI = ps[0][0] + ps[0][1] + ps[0][2] + ps[0][3] + b1i;
        float ZG = ps[1][0] + ps[1][1] + ps[1][2] + ps[1][3] + b1g;
        float ZO = ps[2][0] + ps[2][1] + ps[2][2] + ps[2][3] + b1o;
        cst1(&s1[wb], sigm(ZO) * ftanh(sigm(ZI) * ftanh(ZG)));
      }
    }
    warr(iws, ++g, b);

    // ======== prefetch B: W1/V1 bf16 rows + recon2 (written D_{t-1}/preloop)
    uint2 wB1 = ((const uint2*)(reg + OBW))[tid];
    uint2 wBV; if (hasV1) wBV = ((const uint2*)(reg + OBV))[tid];
    float4 rv2 = cld4(recon2 + tid * 4);
    wwait(iws, g, b);
    // ---- B: nTD1 = s1-recon2; BU1 = W1@nTD1+b; recon1 = V1@s1+b; TD1<-nTD1; loss += lam*|nTD1|
    {
      float4 sv = cld4(s1 + tid * 4);
      float4 d = make_float4(sv.x - rv2.x, sv.y - rv2.y, sv.z - rv2.z, sv.w - rv2.w);
      float pw = wredsum(bdot2(wB1, d));
      if (lane == 0) ps[0][wv] = pw;
      if (hasV1) {
        float pv = wredsum(bdot2(wBV, sv));
        if (lane == 0) ps[1][wv] = pv;
      }
      if (b == 0) {
        cst2(TD1 + tid * 4, d.x, d.y);
        cst2(TD1 + tid * 4 + 2, d.z, d.w);
        float l = wredsum(fabsf(d.x) + fabsf(d.y) + fabsf(d.z) + fabsf(d.w));
        if (lane == 0) ps[2][wv] = l;
      }
      __syncthreads();
      if (tid == 0) {
        cst1(&BU1[wb], ps[0][0] + ps[0][1] + ps[0][2] + ps[0][3] + w1br);
        if (hasV1) cst1(&recon1[vb], ps[1][0] + ps[1][1] + ps[1][2] + ps[1][3] + v1br);
        if (b == 0) loss += lam * (ps[2][0] + ps[2][1] + ps[2][2] + ps[2][3]);
      }
    }
    warr(iws, ++g, b);

    // ======== prefetch C: Wi2 bf16 rows + TD2 for waves 2,3 (written D_{t-1}/preloop)
    uint4 wCi = ((const uint4*)(reg + OCI))[tid];
    uint4 wCg = ((const uint4*)(reg + OCG))[tid];
    uint4 wCo = ((const uint4*)(reg + OCO))[tid];
    float4 tC0, tC1;
    if (wv >= 2) { tC0 = cld4(TD2 + tid * 8 - 1024); tC1 = cld4(TD2 + tid * 8 - 1020); }
    wwait(iws, g, b);
    // ---- C: s2 = lstm(Wi2 @ [BU1;TD2] + b2)
    {
      float4 v0, v1;
      if (wv < 2) { v0 = cld4(BU1 + tid * 8); v1 = cld4(BU1 + tid * 8 + 4); }
      else { v0 = tC0; v1 = tC1; }
      float zi = wredsum(bdot4(wCi, v0, v1));
      float zg = wredsum(bdot4(wCg, v0, v1));
      float zo = wredsum(bdot4(wCo, v0, v1));
      if (lane == 0) { ps[0][wv] = zi; ps[1][wv] = zg; ps[2][wv] = zo; }
      __syncthreads();
      if (tid == 0) {
        float ZI = ps[0][0] + ps[0][1] + ps[0][2] + ps[0][3] + b2i;
        float ZG = ps[1][0] + ps[1][1] + ps[1][2] + ps[1][3] + b2g;
        float ZO = ps[2][0] + ps[2][1] + ps[2][2] + ps[2][3] + b2o;
        cst1(&s2[wb], sigm(ZO) * ftanh(sigm(ZI) * ftanh(ZG)));
      }
    }
    warr(iws, ++g, b);

    // ======== prefetch D: W2/V2 bf16 rows + recon3 (written F_{t-1}/preloop)
    uint2 wD2 = ((const uint2*)(reg + ODW))[tid];
    uint2 wDV = ((const uint2*)(reg + ODV))[tid];
    float4 rv3 = cld4(recon3 + tid * 4);
    wwait(iws, g, b);
    // ---- D: nTD2 = s2-recon3; BU2 = W2@nTD2+b; recon2 = V2@s2+b; TD2<-nTD2; loss += lam2*|nTD2|
    {
      float4 sv = cld4(s2 + tid * 4);
      float4 d = make_float4(sv.x - rv3.x, sv.y - rv3.y, sv.z - rv3.z, sv.w - rv3.w);
      float pw = wredsum(bdot2(wD2, d));
      float pv = wredsum(bdot2(wDV, sv));
      if (lane == 0) { ps[0][wv] = pw; ps[1][wv] = pv; }
      if (b == 0) {
        cst2(TD2 + tid * 4, d.x, d.y);
        cst2(TD2 + tid * 4 + 2, d.z, d.w);
        float l = wredsum(fabsf(d.x) + fabsf(d.y) + fabsf(d.z) + fabsf(d.w));
        if (lane == 0) ps[2][wv] = l;
      }
      __syncthreads();
      if (tid == 0) {
        cst1(&BU2[wb],    ps[0][0] + ps[0][1] + ps[0][2] + ps[0][3] + w2br);
        cst1(&recon2[wb], ps[1][0] + ps[1][1] + ps[1][2] + ps[1][3] + v2br);
        if (b == 0) loss += lam2 * (ps[2][0] + ps[2][1] + ps[2][2] + ps[2][3]);
      }
    }
    warr(iws, ++g, b);

    // ======== prefetch E: Wi3 bf16 rows
    uint2 wEi = ((const uint2*)(reg + OEI))[tid];
    uint2 wEg = ((const uint2*)(reg + OEG))[tid];
    uint2 wEo = ((const uint2*)(reg + OEO))[tid];
    wwait(iws, g, b);
    // ---- E: s3 = lstm(Wi3 @ BU2 + b3)
    {
      float4 v0 = cld4(BU2 + tid * 4);
      float zi = wredsum(bdot2(wEi, v0));
      float zg = wredsum(bdot2(wEg, v0));
      float zo = wredsum(bdot2(wEo, v0));
      if (lane == 0) { ps[0][wv] = zi; ps[1][wv] = zg; ps[2][wv] = zo; }
      __syncthreads();
      if (tid == 0) {
        float ZI = ps[0][0] + ps[0][1] + ps[0][2] + ps[0][3] + b3i;
        float ZG = ps[1][0] + ps[1][1] + ps[1][2] + ps[1][3] + b3g;
        float ZO = ps[2][0] + ps[2][1] + ps[2][2] + ps[2][3] + b3o;
        cst1(&s3[wb], sigm(ZO) * ftanh(sigm(ZI) * ftanh(ZG)));
      }
    }
    warr(iws, ++g, b);

    // ======== prefetch F: V3 bf16 row; wave1: W0 row (fp32), x_{t+1}, recon1 (written B_t)
    uint2 wFV = ((const uint2*)(reg + OFV))[tid];
    float4 w0r, xnx, rc1;
    if (wv == 1 && lane < 14) {
      const int tn = (t < TT - 1) ? (t + 1) : (TT - 1);
      w0r = ((const float4*)(W0w + wb * CC))[lane];
      xnx = ((const float4*)(inp + tn * CC))[lane];
      rc1 = cld4(recon1 + lane * 4);
    }
    wwait(iws, g, b);
    // ---- F: recon3 = V3@s3+b ; BU0(t+1) = W0@(x_{t+1}-recon1)+W0b ; loss += |nTD0|
    {
      float4 v0 = cld4(s3 + tid * 4);
      float pv = wredsum(bdot2(wFV, v0));
      if (lane == 0) ps[0][wv] = pv;
      if (t < TT - 1 && wv == 1) {
        float acc = 0.f, ls = 0.f;
        if (lane < 14) {
          float4 dd = make_float4(xnx.x - rc1.x, xnx.y - rc1.y, xnx.z - rc1.z, xnx.w - rc1.w);
          acc = dot4(w0r, dd);
          ls = fabsf(dd.x) + fabsf(dd.y) + fabsf(dd.z) + fabsf(dd.w);
        }
        acc = wredsum(acc);
        ls  = wredsum(ls);
        if (lane == 0) { cst1(&BU0[wb], acc + w0br); ps[1][0] = ls; }
      }
      __syncthreads();
      if (tid == 0) {
        cst1(&recon3[wb], ps[0][0] + ps[0][1] + ps[0][2] + ps[0][3] + v3br);
        if (b == 0 && t < TT - 1) loss += ps[1][0];
      }
    }
    warr(iws, ++g, b);
  }

  if (b == 0 && tid == 0) out[0] = loss;
}

extern "C" void kernel_launch(void* const* d_in, const int* in_sizes, int n_in,
                              void* d_out, int out_size, void* d_ws, size_t ws_size,
                              hipStream_t stream) {
  const float* inp = (const float*)d_in[0];
  const float* W0w = (const float*)d_in[1];
  const float* W0b = (const float*)d_in[2];
  const float* W1w = (const float*)d_in[3];
  const float* W1b = (const float*)d_in[4];
  const float* W2w = (const float*)d_in[5];
  const float* W2b = (const float*)d_in[6];
  const float* Wi1 = (const float*)d_in[7];
  const float* b1  = (const float*)d_in[8];
  const float* Wi2 = (const float*)d_in[9];
  const float* b2  = (const float*)d_in[10];
  const float* Wi3 = (const float*)d_in[11];
  const float* b3  = (const float*)d_in[12];
  const float* V1w = (const float*)d_in[13];
  const float* V1b = (const float*)d_in[14];
  const float* V2w = (const float*)d_in[15];
  const float* V2b = (const float*)d_in[16];
  const float* V3w = (const float*)d_in[17];
  const float* V3b = (const float*)d_in[18];
  const int*   itn = (const int*)d_in[19];

  int*            iws = (int*)d_ws;                                  // 136 KB strided slots+flags
  float*          fws = (float*)((char*)d_ws + 147456);              // carry/stage vectors (~41 KB)
  unsigned short* wbf = (unsigned short*)((char*)d_ws + 262144);     // 1024 × 40 KB bf16 weight regions

  hipLaunchKernelGGL(predcells, dim3(GRID), dim3(NT), 0, stream,
                     inp, W0w, W0b, W1w, W1b, W2w, W2b,
                     Wi1, b1, Wi2, b2, Wi3, b3,
                     V1w, V1b, V2w, V2b, V3w, V3b, itn,
                     (float*)d_out, iws, fws, wbf);
}

// Round 8
// 1109.807 us; speedup vs baseline: 3.7900x; 1.5363x over previous
//
#include <hip/hip_runtime.h>

#define CC 56
#define TT 64
#define GRID 1024
#define NT 256
#define NFLAG 64
#define SS 32                    // 128 B stride between sync slots
#define FB (GRID * SS)           // flag base (int index)
#define AGENT __HIP_MEMORY_SCOPE_AGENT

// ---- ws byte offsets
#define OFF_FWS   147456         // carry vectors (floats)
#define OFF_W1BF  262144         // W1 bf16, 2 MB
#define OFF_W2BF  2359296       // W2 bf16, 2 MB
#define OFF_PRIV  4456448       // 1024 × 32 KB private regions
#define PRIVB     32768

// ---- private region offsets (ushort units)
#define PM2  0                   // M2 rows (i,g,o) 3×1024 bf16
#define PM3  3072
#define PW1R 6144                // Wi1 right-half rows
#define PW2R 9216                // Wi2 right-half rows
#define PV2  12288
#define PV3  13312
#define PV1  14336
#define PA0  15360               // A0 fp32 3×56 at byte 30720

// ---- fws float offsets (all coherent)
#define FS1   0
#define FS2   1024
#define FS3   2048
#define FTD1  3072               // two parity slots 3072/4096
#define FTD2  5120               // two parity slots 5120/6144
#define FRC1  7168               // 64

static __device__ __forceinline__ float wredsum(float v) {
#pragma unroll
  for (int m = 32; m; m >>= 1) v += __shfl_xor(v, m, 64);
  return v;
}
static __device__ __forceinline__ float sigm(float x) { return 1.f / (1.f + __expf(-x)); }
static __device__ __forceinline__ float ftanh(float x) {
  x = fminf(15.f, fmaxf(-15.f, x));
  float e = __expf(2.f * x);
  return (e - 1.f) / (e + 1.f);
}

// coherent accessors (agent-scope, L2-bypassing) for repeatedly-rewritten data
static __device__ __forceinline__ float2 cld2(const float* p) {
  unsigned long long u = __hip_atomic_load((const unsigned long long*)p, __ATOMIC_RELAXED, AGENT);
  union { unsigned long long u; float2 f; } c; c.u = u; return c.f;
}
static __device__ __forceinline__ float4 cld4(const float* p) {
  float2 a = cld2(p), b = cld2(p + 2);
  return make_float4(a.x, a.y, b.x, b.y);
}
static __device__ __forceinline__ float cld1(const float* p) {
  return __uint_as_float(__hip_atomic_load((const unsigned int*)p, __ATOMIC_RELAXED, AGENT));
}
static __device__ __forceinline__ void cst1(float* p, float v) {
  __hip_atomic_store((unsigned int*)p, __float_as_uint(v), __ATOMIC_RELAXED, AGENT);
}
static __device__ __forceinline__ void cstu2(unsigned* p, unsigned a, unsigned b) {
  unsigned long long u = (unsigned long long)a | ((unsigned long long)b << 32);
  __hip_atomic_store((unsigned long long*)p, u, __ATOMIC_RELAXED, AGENT);
}
static __device__ __forceinline__ int ldi(const int* p) {
  return __hip_atomic_load(p, __ATOMIC_RELAXED, AGENT);
}
static __device__ __forceinline__ void sti(int* p, int v) {
  __hip_atomic_store(p, v, __ATOMIC_RELAXED, AGENT);
}

// bf16 pack (RNE) + dot helpers
static __device__ __forceinline__ unsigned bfp(float lo, float hi) {
  unsigned a = __float_as_uint(lo), b = __float_as_uint(hi);
  a = (a + 0x7fffu + ((a >> 16) & 1u)) >> 16;
  b = (b + 0x7fffu + ((b >> 16) & 1u)) >> 16;
  return a | (b << 16);
}
static __device__ __forceinline__ float blo(unsigned u) { return __uint_as_float(u << 16); }
static __device__ __forceinline__ float bhi(unsigned u) { return __uint_as_float(u & 0xffff0000u); }
static __device__ __forceinline__ float bdot2(uint2 w, float4 v) {
  float r = blo(w.x) * v.x;
  r = fmaf(bhi(w.x), v.y, r);
  r = fmaf(blo(w.y), v.z, r);
  r = fmaf(bhi(w.y), v.w, r);
  return r;
}

// round-5/7 master-relay barrier (verified). No init: 0xAA poison < 0, g monotone > 0.
static __device__ __forceinline__ void warr(int* iws, int g, int b) {
  __syncthreads();
  if (threadIdx.x == 0) sti(iws + SS * b, g);
}
static __device__ __forceinline__ void wwait(int* iws, int g, int b) {
  if (b == 0) {
    const int* p0 = iws + SS * threadIdx.x;
    for (;;) {
      int a0 = ldi(p0), a1 = ldi(p0 + SS * 256), a2 = ldi(p0 + SS * 512), a3 = ldi(p0 + SS * 768);
      if (a0 >= g && a1 >= g && a2 >= g && a3 >= g) break;
      __builtin_amdgcn_s_sleep(1);
    }
    __syncthreads();
    if (threadIdx.x < NFLAG) sti(iws + FB + SS * threadIdx.x, g);
  } else {
    if (threadIdx.x == 0)
      while (ldi(iws + FB + SS * (b & (NFLAG - 1))) < g) __builtin_amdgcn_s_sleep(1);
  }
  __asm__ __volatile__("" ::: "memory");
  __syncthreads();
}

// 1024-dot: wave-local, 16 fp32/lane (used for prologue constants)
static __device__ __forceinline__ float dotw(const float* a, const float* c, int lane) {
  const float4* a4 = (const float4*)a;
  const float4* c4 = (const float4*)c;
  float acc = 0.f;
#pragma unroll
  for (int j = 0; j < 4; ++j) {
    float4 x = a4[lane * 4 + j], y = c4[lane * 4 + j];
    acc = fmaf(x.x, y.x, fmaf(x.y, y.y, fmaf(x.z, y.z, fmaf(x.w, y.w, acc))));
  }
  return wredsum(acc);
}

__global__ void __launch_bounds__(NT, 4) predcells(
    const float* __restrict__ inp,
    const float* __restrict__ W0w, const float* __restrict__ W0b,
    const float* __restrict__ W1w, const float* __restrict__ W1b,
    const float* __restrict__ W2w, const float* __restrict__ W2b,
    const float* __restrict__ Wi1, const float* __restrict__ b1,
    const float* __restrict__ Wi2, const float* __restrict__ b2,
    const float* __restrict__ Wi3, const float* __restrict__ b3,
    const float* __restrict__ V1w, const float* __restrict__ V1b,
    const float* __restrict__ V2w, const float* __restrict__ V2b,
    const float* __restrict__ V3w, const float* __restrict__ V3b,
    const int* __restrict__ itn,
    float* __restrict__ out, char* ws)
{
  const int tid = threadIdx.x;
  const int lane = tid & 63;
  const int wv = tid >> 6;
  const int b = blockIdx.x;
  const bool hasV1 = (b < CC);

  int* iws = (int*)ws;
  float* fws = (float*)(ws + OFF_FWS);
  unsigned short* w1bf = (unsigned short*)(ws + OFF_W1BF);
  unsigned short* w2bf = (unsigned short*)(ws + OFF_W2BF);
  unsigned short* priv = (unsigned short*)(ws + OFF_PRIV + (size_t)b * PRIVB);

  __shared__ float arow[6][1024];           // GEMM staging (24 KB)
  __shared__ float psX[6][4], psP[3][4], psA[3];
  __shared__ float cs1[3], cs2[3], cs3[3];

  const int gofs = (wv == 0) ? 0 : ((wv == 1) ? 2048 : 3072);  // i,g,o rows for waves 0..2

  // ======== phase 0: convert W1/W2 row b to shared bf16 (coherent stores)
  {
    float4 r1 = ((const float4*)(W1w + (size_t)b * 1024))[tid];
    cstu2((unsigned*)(w1bf + (size_t)b * 1024 + 4 * tid), bfp(r1.x, r1.y), bfp(r1.z, r1.w));
    float4 r2 = ((const float4*)(W2w + (size_t)b * 1024))[tid];
    cstu2((unsigned*)(w2bf + (size_t)b * 1024 + 4 * tid), bfp(r2.x, r2.y), bfp(r2.z, r2.w));
  }
  warr(iws, 1, b);

  // ======== phase 1 (during barrier-1 window): local prep
  const float lam = (itn[0] <= 1000) ? 1e-4f : 1e-2f;
  const float lam2 = lam * lam;
  const float v1b_b = hasV1 ? V1b[b] : 0.f;
  const float v2b_b = V2b[b];
  const float v3b_b = V3b[b];
  float l0 = 0.f, l1 = 0.f, l2 = 0.f;  // loss partials, block0 registers

  if (wv < 3) {
    // constants c1/c2/c3 per gate row
    float c1v = b1[b + gofs] + dotw(Wi1 + (size_t)(b + gofs) * 2048, W0b, lane);
    float c2v = b2[b + gofs] + dotw(Wi2 + (size_t)(b + gofs) * 2048, W1b, lane);
    float c3v = b3[b + gofs] + dotw(Wi3 + (size_t)(b + gofs) * 1024, W2b, lane);
    if (lane == 0) { cs1[wv] = c1v; cs2[wv] = c2v; cs3[wv] = c3v; }
    // A0 = Wi1_L @ W0 (3×56): lanes own columns, k-loop broadcast
    if (lane < CC) {
      const float* wr = Wi1 + (size_t)(b + gofs) * 2048;
      float acc = 0.f;
      for (int k = 0; k < 1024; ++k) acc = fmaf(wr[k], W0w[k * CC + lane], acc);
      ((float*)(priv + PA0))[wv * CC + lane] = acc;
    }
    // private bf16: Wi1R / Wi2R gate rows
    {
      float4 x = ((const float4*)(Wi1 + (size_t)(b + gofs) * 2048 + 1024))[lane];
      ((uint2*)(priv + PW1R + wv * 1024))[lane] = make_uint2(bfp(x.x, x.y), bfp(x.z, x.w));
      float4 y = ((const float4*)(Wi2 + (size_t)(b + gofs) * 2048 + 1024))[lane];
      ((uint2*)(priv + PW2R + wv * 1024))[lane] = make_uint2(bfp(y.x, y.y), bfp(y.z, y.w));
    }
  } else {
    // wave 3: V2/V3/V1 rows to private bf16 (256 f4-chunks / 64 lanes = 4 each)
#pragma unroll
    for (int j = 0; j < 4; ++j) {
      int i = lane * 4 + j;
      float4 a = ((const float4*)(V2w + (size_t)b * 1024))[i];
      ((uint2*)(priv + PV2))[i] = make_uint2(bfp(a.x, a.y), bfp(a.z, a.w));
      float4 c = ((const float4*)(V3w + (size_t)b * 1024))[i];
      ((uint2*)(priv + PV3))[i] = make_uint2(bfp(c.x, c.y), bfp(c.z, c.w));
      if (hasV1) {
        float4 d = ((const float4*)(V1w + (size_t)b * 1024))[i];
        ((uint2*)(priv + PV1))[i] = make_uint2(bfp(d.x, d.y), bfp(d.z, d.w));
      }
    }
  }
  __syncthreads();
  // s1_0 = act(A0@x_0 + c1); publish s1_0, TD1_0(par0)=s1_0, s3=0, TD2(par1)=0
  if (wv < 3) {
    float p = 0.f, ax = 0.f;
    if (lane < CC) {
      float xv = inp[lane];
      p = ((const float*)(priv + PA0))[wv * CC + lane] * xv;
      ax = fabsf(xv);
    }
    p = wredsum(p);
    ax = wredsum(ax);
    if (lane == 0) psA[wv] = p;
    if (b == 0 && wv == 0) l0 += ax;   // |nTD0_0| = Σ|x_0|
  }
  __syncthreads();
  if (tid == 0) {
    float s1v = sigm(psA[2] + cs1[2]) * ftanh(sigm(psA[0] + cs1[0]) * ftanh(psA[1] + cs1[1]));
    cst1(fws + FS1 + b, s1v);
    cst1(fws + FTD1 + b, s1v);        // parity 0
    cst1(fws + FS3 + b, 0.f);
    cst1(fws + FTD2 + 1024 + b, 0.f); // parity 1 (read by pre-X_0)
  }
  wwait(iws, 1, b);

  // ======== phase 2: GEMMs M2 = Wi2_L@W1, M3 = Wi3@W2 → private bf16
  {
#pragma unroll
    for (int w = 0; w < 3; ++w) {
      int go = (w == 0) ? 0 : ((w == 1) ? 2048 : 3072);
      ((float4*)arow[w])[tid]     = ((const float4*)(Wi2 + (size_t)(b + go) * 2048))[tid];
      ((float4*)arow[3 + w])[tid] = ((const float4*)(Wi3 + (size_t)(b + go) * 1024))[tid];
    }
    __syncthreads();
    float ac[12];
#pragma unroll
    for (int j = 0; j < 12; ++j) ac[j] = 0.f;
    const uint2* wsrc = (const uint2*)w1bf;
#pragma unroll 4
    for (int k = 0; k < 1024; ++k) {
      uint2 wp = wsrc[k * 256 + tid];
      float f0 = blo(wp.x), f1 = bhi(wp.x), f2 = blo(wp.y), f3 = bhi(wp.y);
      float ai = arow[0][k], ag = arow[1][k], ao = arow[2][k];
      ac[0] = fmaf(ai, f0, ac[0]); ac[1] = fmaf(ai, f1, ac[1]); ac[2] = fmaf(ai, f2, ac[2]); ac[3] = fmaf(ai, f3, ac[3]);
      ac[4] = fmaf(ag, f0, ac[4]); ac[5] = fmaf(ag, f1, ac[5]); ac[6] = fmaf(ag, f2, ac[6]); ac[7] = fmaf(ag, f3, ac[7]);
      ac[8] = fmaf(ao, f0, ac[8]); ac[9] = fmaf(ao, f1, ac[9]); ac[10] = fmaf(ao, f2, ac[10]); ac[11] = fmaf(ao, f3, ac[11]);
    }
#pragma unroll
    for (int w = 0; w < 3; ++w)
      ((uint2*)(priv + PM2 + w * 1024))[tid] =
          make_uint2(bfp(ac[w * 4 + 0], ac[w * 4 + 1]), bfp(ac[w * 4 + 2], ac[w * 4 + 3]));
#pragma unroll
    for (int j = 0; j < 12; ++j) ac[j] = 0.f;
    wsrc = (const uint2*)w2bf;
#pragma unroll 4
    for (int k = 0; k < 1024; ++k) {
      uint2 wp = wsrc[k * 256 + tid];
      float f0 = blo(wp.x), f1 = bhi(wp.x), f2 = blo(wp.y), f3 = bhi(wp.y);
      float ai = arow[3][k], ag = arow[4][k], ao = arow[5][k];
      ac[0] = fmaf(ai, f0, ac[0]); ac[1] = fmaf(ai, f1, ac[1]); ac[2] = fmaf(ai, f2, ac[2]); ac[3] = fmaf(ai, f3, ac[3]);
      ac[4] = fmaf(ag, f0, ac[4]); ac[5] = fmaf(ag, f1, ac[5]); ac[6] = fmaf(ag, f2, ac[6]); ac[7] = fmaf(ag, f3, ac[7]);
      ac[8] = fmaf(ao, f0, ac[8]); ac[9] = fmaf(ao, f1, ac[9]); ac[10] = fmaf(ao, f2, ac[10]); ac[11] = fmaf(ao, f3, ac[11]);
    }
#pragma unroll
    for (int w = 0; w < 3; ++w)
      ((uint2*)(priv + PM3 + w * 1024))[tid] =
          make_uint2(bfp(ac[w * 4 + 0], ac[w * 4 + 1]), bfp(ac[w * 4 + 2], ac[w * 4 + 3]));
  }
  warr(iws, 2, b);

  // ======== recurrent loop: 2 barriers per step
  int g = 2;
  const uint2* pm2 = (const uint2*)(priv + PM2);
  const uint2* pm3 = (const uint2*)(priv + PM3);
  const uint2* pw1r = (const uint2*)(priv + PW1R);
  const uint2* pw2r = (const uint2*)(priv + PW2R);
  const uint2* pv2 = (const uint2*)(priv + PV2);
  const uint2* pv3 = (const uint2*)(priv + PV3);
  const uint2* pv1 = (const uint2*)(priv + PV1);
  const float* a0p = (const float*)(priv + PA0);

  for (int t = 0; t < TT; ++t) {
    const int par = t & 1;
    float* td1cur = fws + FTD1 + par * 1024;         // TD1_t
    float* td1nxt = fws + FTD1 + (par ^ 1) * 1024;   // TD1_{t+1}
    float* td2old = fws + FTD2 + (par ^ 1) * 1024;   // TD2_{t-1}
    float* td2cur = fws + FTD2 + par * 1024;         // TD2_t

    // ---- pre-X (1-barrier-old data; dbuf makes TD2_{t-1} stable)
    uint2 wm2[3]; wm2[0] = pm2[tid]; wm2[1] = pm2[256 + tid]; wm2[2] = pm2[512 + tid];
    uint2 wv3 = pv3[tid];
    uint2 wv1; if (hasV1) wv1 = pv1[tid];
    {
      float4 v = cld4(td2old + 4 * tid);
      uint2 wr0 = pw2r[tid], wr1 = pw2r[256 + tid], wr2 = pw2r[512 + tid];
      float p0 = wredsum(bdot2(wr0, v));
      float p1 = wredsum(bdot2(wr1, v));
      float p2 = wredsum(bdot2(wr2, v));
      if (lane == 0) { psP[0][wv] = p0; psP[1][wv] = p1; psP[2][wv] = p2; }
    }
    wwait(iws, g, b);
    // ---- X_t: s2_t = act(M2@TD1_t + Wi2R@TD2_{t-1} + c2); TD2_t; rc1_t; loss|TD1_t|
    {
      float4 vtd1 = cld4(td1cur + 4 * tid);
      float4 vs3  = cld4(fws + FS3 + 4 * tid);
      float p0 = wredsum(bdot2(wm2[0], vtd1));
      float p1 = wredsum(bdot2(wm2[1], vtd1));
      float p2 = wredsum(bdot2(wm2[2], vtd1));
      float p3 = wredsum(bdot2(wv3, vs3));
      if (lane == 0) { psX[0][wv] = p0; psX[1][wv] = p1; psX[2][wv] = p2; psX[3][wv] = p3; }
      if (hasV1) {
        float4 vs1 = cld4(fws + FS1 + 4 * tid);
        float pv = wredsum(bdot2(wv1, vs1));
        if (lane == 0) psX[4][wv] = pv;
      }
      if (b == 0) {
        float al = wredsum(fabsf(vtd1.x) + fabsf(vtd1.y) + fabsf(vtd1.z) + fabsf(vtd1.w));
        if (lane == 0) psX[5][wv] = al;
      }
      __syncthreads();
      if (tid == 0) {
        float zi = psX[0][0] + psX[0][1] + psX[0][2] + psX[0][3] + psP[0][0] + psP[0][1] + psP[0][2] + psP[0][3] + cs2[0];
        float zg = psX[1][0] + psX[1][1] + psX[1][2] + psX[1][3] + psP[1][0] + psP[1][1] + psP[1][2] + psP[1][3] + cs2[1];
        float zo = psX[2][0] + psX[2][1] + psX[2][2] + psX[2][3] + psP[2][0] + psP[2][1] + psP[2][2] + psP[2][3] + cs2[2];
        float s2v = sigm(zo) * ftanh(sigm(zi) * ftanh(zg));
        float rc3v = (t == 0) ? 0.f : (psX[3][0] + psX[3][1] + psX[3][2] + psX[3][3] + v3b_b);
        cst1(fws + FS2 + b, s2v);
        cst1(td2cur + b, s2v - rc3v);
        if (hasV1) cst1(fws + FRC1 + b, psX[4][0] + psX[4][1] + psX[4][2] + psX[4][3] + v1b_b);
        if (b == 0) l1 += psX[5][0] + psX[5][1] + psX[5][2] + psX[5][3];
      }
    }
    warr(iws, ++g, b);

    // ---- pre-Y (TD1_t is parity-stable vs Y's TD1_{t+1} writes)
    uint2 wm3[3]; wm3[0] = pm3[tid]; wm3[1] = pm3[256 + tid]; wm3[2] = pm3[512 + tid];
    uint2 wv2 = pv2[tid];
    {
      float4 v = cld4(td1cur + 4 * tid);
      uint2 wr0 = pw1r[tid], wr1 = pw1r[256 + tid], wr2 = pw1r[512 + tid];
      float p0 = wredsum(bdot2(wr0, v));
      float p1 = wredsum(bdot2(wr1, v));
      float p2 = wredsum(bdot2(wr2, v));
      if (lane == 0) { psP[0][wv] = p0; psP[1][wv] = p1; psP[2][wv] = p2; }
    }
    wwait(iws, g, b);
    // ---- Y_t: s3_t = act(M3@TD2_t + c3); s1_{t+1} = act(A0@nTD0_{t+1} + Wi1R@TD1_t + c1);
    //          TD1_{t+1} = s1_{t+1} − (V2@s2_t + v2b); losses |TD2_t|, |nTD0_{t+1}|
    {
      float4 vtd2 = cld4(td2cur + 4 * tid);
      float4 vs2  = cld4(fws + FS2 + 4 * tid);
      float p0 = wredsum(bdot2(wm3[0], vtd2));
      float p1 = wredsum(bdot2(wm3[1], vtd2));
      float p2 = wredsum(bdot2(wm3[2], vtd2));
      float p3 = wredsum(bdot2(wv2, vs2));
      if (lane == 0) { psX[0][wv] = p0; psX[1][wv] = p1; psX[2][wv] = p2; psX[3][wv] = p3; }
      if (b == 0) {
        float al = wredsum(fabsf(vtd2.x) + fabsf(vtd2.y) + fabsf(vtd2.z) + fabsf(vtd2.w));
        if (lane == 0) psX[5][wv] = al;
      }
      // A0 gate dots over nTD0_{t+1} (x clamped at t=63; result unused there for loss)
      if (wv < 3) {
        const int tn = (t < TT - 1) ? (t + 1) : (TT - 1);
        float p = 0.f, ax = 0.f;
        if (lane < CC) {
          float xv = inp[tn * CC + lane];
          float rcv = cld1(fws + FRC1 + lane);
          float nd = xv - rcv;
          p = a0p[wv * CC + lane] * nd;
          ax = fabsf(nd);
        }
        p = wredsum(p);
        ax = wredsum(ax);
        if (lane == 0) psA[wv] = p;
        if (b == 0 && wv == 0 && t < TT - 1) l0 += ax;
      }
      __syncthreads();
      if (tid == 0) {
        float z3i = psX[0][0] + psX[0][1] + psX[0][2] + psX[0][3] + cs3[0];
        float z3g = psX[1][0] + psX[1][1] + psX[1][2] + psX[1][3] + cs3[1];
        float z3o = psX[2][0] + psX[2][1] + psX[2][2] + psX[2][3] + cs3[2];
        cst1(fws + FS3 + b, sigm(z3o) * ftanh(sigm(z3i) * ftanh(z3g)));
        float rc2v = psX[3][0] + psX[3][1] + psX[3][2] + psX[3][3] + v2b_b;
        float z1i = psA[0] + psP[0][0] + psP[0][1] + psP[0][2] + psP[0][3] + cs1[0];
        float z1g = psA[1] + psP[1][0] + psP[1][1] + psP[1][2] + psP[1][3] + cs1[1];
        float z1o = psA[2] + psP[2][0] + psP[2][1] + psP[2][2] + psP[2][3] + cs1[2];
        float s1n = sigm(z1o) * ftanh(sigm(z1i) * ftanh(z1g));
        cst1(fws + FS1 + b, s1n);
        cst1(td1nxt + b, s1n - rc2v);
        if (b == 0) l2 += psX[5][0] + psX[5][1] + psX[5][2] + psX[5][3];
      }
    }
    warr(iws, ++g, b);
  }

  if (b == 0 && tid == 0) out[0] = l0 + lam * l1 + lam2 * l2;
}

extern "C" void kernel_launch(void* const* d_in, const int* in_sizes, int n_in,
                              void* d_out, int out_size, void* d_ws, size_t ws_size,
                              hipStream_t stream) {
  const float* inp = (const float*)d_in[0];
  const float* W0w = (const float*)d_in[1];
  const float* W0b = (const float*)d_in[2];
  const float* W1w = (const float*)d_in[3];
  const float* W1b = (const float*)d_in[4];
  const float* W2w = (const float*)d_in[5];
  const float* W2b = (const float*)d_in[6];
  const float* Wi1 = (const float*)d_in[7];
  const float* b1  = (const float*)d_in[8];
  const float* Wi2 = (const float*)d_in[9];
  const float* b2  = (const float*)d_in[10];
  const float* Wi3 = (const float*)d_in[11];
  const float* b3  = (const float*)d_in[12];
  const float* V1w = (const float*)d_in[13];
  const float* V1b = (const float*)d_in[14];
  const float* V2w = (const float*)d_in[15];
  const float* V2b = (const float*)d_in[16];
  const float* V3w = (const float*)d_in[17];
  const float* V3b = (const float*)d_in[18];
  const int*   itn = (const int*)d_in[19];

  hipLaunchKernelGGL(predcells, dim3(GRID), dim3(NT), 0, stream,
                     inp, W0w, W0b, W1w, W1b, W2w, W2b,
                     Wi1, b1, Wi2, b2, Wi3, b3,
                     V1w, V1b, V2w, V2b, V3w, V3b, itn,
                     (float*)d_out, (char*)d_ws);
}